// Round 18
// baseline (139.440 us; speedup 1.0000x reference)
//
#include <hip/hip_runtime.h>
#include <hip/hip_fp16.h>
#include <math.h>

#define N_NODES 50000
#define N_REL   1000
#define D       128
#define NNZ     800000

#define RB    512                  // rows per k1 bin (full-line write runs)
#define NBIN  98                   // ceil(50000/512)
#define CAP   10240                // slots/bin: mean 8184, sigma ~90
#define CH    2048                 // edges per partition chunk (391 blocks: k1 optimum)
#define NCH   ((NNZ + CH - 1) / CH)   // 391 chunks/blocks
#define K1T   512
#define K1E   (CH / K1T)           // 4 edges/thread
#define QW    2560                 // k2a quarter-window packs (CAP/4)
#define QE    (QW / 512)           // 5 staged packs/thread in k2a
#define SRB   64                   // rows per sub-bin slice
#define SCAP  1536                 // slots per sub-bin (mean 1023, +16 sigma)
#define NSUB  (NBIN * 8)           // 784 sub-bins
#define K0B   2048                 // k0 streaming grid (BW-optimal)

// ===== K0: relation scores (first 1000 waves) + f32->f16 convert (streaming) ====
__global__ void __launch_bounds__(256)
k0_kernel(const float* __restrict__ dual, const float* __restrict__ conv_w,
          const float* __restrict__ conv_b, const float* __restrict__ inlayer,
          float* __restrict__ exp_scores, __half2* __restrict__ hinl) {
    int t = threadIdx.x;
    int gtid = blockIdx.x * 256 + t;
    int lane = t & 63;

    int wid = gtid >> 6;
    if (wid < N_REL) {
        const float* row = dual + (long)wid * D;
        float s = row[lane] * conv_w[lane] + row[lane + 64] * conv_w[lane + 64];
        #pragma unroll
        for (int off = 32; off > 0; off >>= 1) s += __shfl_down(s, off);
        if (lane == 0) {
            float v = s + conv_b[0];
            v = (v >= 0.f) ? v : 0.01f * v;        // leaky_relu
            exp_scores[wid] = expf(v);             // scores ~N(0,1): safe
        }
    }

    // streaming convert at full-grid occupancy (~3 iters/thread)
    const float4* src4 = (const float4*)inlayer;
    uint2* dst2 = (uint2*)hinl;
    for (int i = gtid; i < N_NODES * D / 4; i += K0B * 256) {
        float4 f = src4[i];
        __half2 h0 = __floats2half2_rn(f.x, f.y);
        __half2 h1 = __floats2half2_rn(f.z, f.w);
        uint2 o; o.x = *(unsigned*)&h0; o.y = *(unsigned*)&h1;
        dst2[i] = o;
    }
}

// ===== K1: LDS-sorted bin partition + block denom partial (partition only) ======
// Edge pack (u64): col:16 | rel:10 | rowlocal:9. 98 bins -> ~21-edge (168B) runs.
__global__ void __launch_bounds__(K1T)
k1_kernel(const int* __restrict__ rows, const int* __restrict__ cols,
          const int* __restrict__ rel, const float* __restrict__ exp_scores,
          float* __restrict__ denom, unsigned* __restrict__ bincur,
          unsigned long long* __restrict__ binbuf) {
    __shared__ unsigned long long sbuf[CH];     // 16 KB chunk staging (bin-sorted)
    __shared__ unsigned char sbin[CH];          // 2 KB per-slot bin id (98 < 256)
    __shared__ unsigned lcnt[NBIN], lstart[NBIN], lgb[NBIN];
    __shared__ float fpart[8];
    __shared__ unsigned w0sum;
    int t = threadIdx.x;
    int lane = t & 63, w = t >> 6;

    if (t < NBIN) lcnt[t] = 0;
    __syncthreads();

    int n = NNZ - blockIdx.x * CH; if (n > CH) n = CH;   // tail = 1280 (mult of 4)
    int base4 = blockIdx.x * (CH / 4);

    int       ebin[K1E];
    unsigned  erank[K1E];
    unsigned long long epack[K1E];
    float dsum = 0.f;
    bool has = (4 * t < n);
    int4 rr, cc, qq;
    if (has) {
        rr = ((const int4*)rows)[base4 + t];
        cc = ((const int4*)cols)[base4 + t];
        qq = ((const int4*)rel)[base4 + t];
    }
    #pragma unroll
    for (int k = 0; k < K1E; ++k) {
        if (has) {
            int r = (k == 0) ? rr.x : (k == 1) ? rr.y : (k == 2) ? rr.z : rr.w;
            int c = (k == 0) ? cc.x : (k == 1) ? cc.y : (k == 2) ? cc.z : cc.w;
            int q = (k == 0) ? qq.x : (k == 1) ? qq.y : (k == 2) ? qq.z : qq.w;
            int b = r >> 9;
            epack[k] = (unsigned long long)(unsigned)c
                     | ((unsigned long long)(unsigned)q << 16)
                     | ((unsigned long long)(unsigned)(r & 511) << 26);
            ebin[k] = b;
            erank[k] = atomicAdd(&lcnt[b], 1u);
            dsum += exp_scores[q];                 // 4KB table: L1-resident
        } else ebin[k] = -1;
    }
    // wave-level denom partial
    #pragma unroll
    for (int off = 32; off > 0; off >>= 1) dsum += __shfl_down(dsum, off);
    if (lane == 0) fpart[w] = dsum;
    __syncthreads();

    // exclusive scan of 98 bin counts (2 waves) + reserve global runs
    unsigned v = (t < NBIN) ? lcnt[t] : 0u;
    if (t < 128) {
        #pragma unroll
        for (int off = 1; off < 64; off <<= 1) {
            unsigned y = __shfl_up(v, off);
            if (lane >= off) v += y;
        }
        if (t == 63) w0sum = v;
    }
    if (t == 0) {                          // one denom atomic per block
        float s = 0.f;
        #pragma unroll
        for (int k = 0; k < 8; ++k) s += fpart[k];
        atomicAdd(denom, s);
    }
    __syncthreads();
    if (t >= 64 && t < 128) v += w0sum;
    if (t < NBIN) {
        lstart[t] = v - lcnt[t];
        lgb[t] = atomicAdd(&bincur[t * 16], lcnt[t]);   // padded cursors: 1/line
    }
    __syncthreads();

    // LDS scatter into bin-sorted order
    #pragma unroll
    for (int k = 0; k < K1E; ++k) {
        if (ebin[k] >= 0) {
            unsigned p = lstart[ebin[k]] + erank[k];
            sbuf[p] = epack[k];
            sbin[p] = (unsigned char)ebin[k];
        }
    }
    __syncthreads();

    // coalesced run writes: ~21-edge (168B) runs -> mostly full 64B lines
    #pragma unroll
    for (int k = 0; k < K1E; ++k) {
        int j = k * K1T + t;
        if (j < n) {
            int b = sbin[j];
            unsigned slot = lgb[b] + (unsigned)j - lstart[b];
            if (slot < CAP)
                binbuf[(unsigned long long)b * CAP + slot] = sbuf[j];
        }
    }
}

// ===== K2a: repartition bin -> 8 slice sub-bins (each edge read/written once) ====
// Block = (bin, quarter-window). Runs avg 320 edges (1.3KB): fully line-aligned.
// Out pack (u32): col:16 | rel:10 | row6(within slice) @26.
__global__ void __launch_bounds__(512)
k2a_kernel(const unsigned* __restrict__ bincur,
           const unsigned long long* __restrict__ binbuf,
           unsigned* __restrict__ scur, unsigned* __restrict__ subbuf) {
    __shared__ unsigned sbuf[QW];          // 10 KB slice-sorted packs
    __shared__ unsigned char ssl[QW];      // 2.5 KB slice ids
    __shared__ unsigned lcnt[8], lstart[8], lgb[8];
    int t = threadIdx.x;
    int b = blockIdx.x >> 2;               // bin 0..97
    int q = blockIdx.x & 3;                // quarter window
    unsigned nb = bincur[b * 16]; if (nb > CAP) nb = CAP;
    int lo = q * QW;
    int n = (int)nb - lo; if (n > QW) n = QW; if (n < 0) n = 0;

    if (t < 8) lcnt[t] = 0;
    __syncthreads();

    unsigned pk32[QE]; int esl[QE]; unsigned erank[QE];
    #pragma unroll
    for (int k = 0; k < QE; ++k) {
        int j = k * 512 + t;
        if (j < n) {
            unsigned long long pk = binbuf[(unsigned long long)b * CAP + lo + j];
            unsigned u = (unsigned)(pk >> 26) & 511u;
            int s = (int)(u >> 6);
            pk32[k] = ((unsigned)pk & 0x3FFFFFFu) | ((u & 63u) << 26);
            esl[k] = s;
            erank[k] = atomicAdd(&lcnt[s], 1u);
        } else esl[k] = -1;
    }
    __syncthreads();

    if (t < 8) lgb[t] = atomicAdd(&scur[(b * 8 + t) * 16], lcnt[t]);
    if (t == 0) {
        unsigned acc = 0;
        #pragma unroll
        for (int s = 0; s < 8; ++s) { lstart[s] = acc; acc += lcnt[s]; }
    }
    __syncthreads();

    #pragma unroll
    for (int k = 0; k < QE; ++k) {
        if (esl[k] >= 0) {
            unsigned p = lstart[esl[k]] + erank[k];
            sbuf[p] = pk32[k];
            ssl[p] = (unsigned char)esl[k];
        }
    }
    __syncthreads();

    // coalesced run writes: avg 320-edge (1.3KB) runs
    #pragma unroll
    for (int k = 0; k < QE; ++k) {
        int j = k * 512 + t;
        if (j < n) {
            int s = ssl[j];
            unsigned slot = lgb[s] + (unsigned)j - lstart[s];
            if (slot < SCAP)
                subbuf[(unsigned)(b * 8 + s) * SCAP + slot] = sbuf[j];
        }
    }
}

// ===== K3: gather — block = sub-bin; reads own 4KB contiguous list ONCE ========
__global__ void __launch_bounds__(512)
k3_kernel(const unsigned* __restrict__ scur, const unsigned* __restrict__ subbuf,
          const float* __restrict__ exp_scores, const float* __restrict__ denom,
          const __half2* __restrict__ hinl, float* __restrict__ out) {
    __shared__ unsigned list[SCAP];        // 6 KB row-sorted (col|rel<<16)
    __shared__ unsigned cnt[SRB], ex[SRB], cur[SRB];
    int t = threadIdx.x, lane = t & 63, w = t >> 6;
    int sid = blockIdx.x;                  // sub-bin 0..783
    int b = sid >> 3, sub = sid & 7;
    unsigned n = scur[sid * 16]; if (n > SCAP) n = SCAP;
    const unsigned* sb = subbuf + (unsigned)sid * SCAP;

    if (t < SRB) cnt[t] = 0;
    float inv = 1.0f / *denom;             // complete after k1; uniform scalar
    __syncthreads();

    // single read of own sub-bin: register-stage + row histogram
    unsigned pkr[3];                       // SCAP/512 = 3, static indexing
    #pragma unroll
    for (int k = 0; k < 3; ++k) {
        int e = k * 512 + t;
        if (e < (int)n) {
            pkr[k] = sb[e];                // contiguous, coalesced
            atomicAdd(&cnt[pkr[k] >> 26], 1u);
        }
    }
    __syncthreads();

    // wave 0: exclusive scan of 64 row counts
    if (t < 64) {
        unsigned c0 = cnt[t];
        unsigned v = c0;
        #pragma unroll
        for (int off = 1; off < 64; off <<= 1) {
            unsigned y = __shfl_up(v, off);
            if (lane >= off) v += y;
        }
        ex[t] = v - c0;
        cur[t] = v - c0;
    }
    __syncthreads();

    // reg -> LDS row-sorted scatter
    #pragma unroll
    for (int k = 0; k < 3; ++k) {
        int e = k * 512 + t;
        if (e < (int)n) {
            unsigned idx = atomicAdd(&cur[pkr[k] >> 26], 1u);
            if (idx < SCAP) list[idx] = pkr[k] & 0x3FFFFFFu;
        }
    }
    __syncthreads();

    // gather: wave w owns rows w*8 .. w*8+7; quad engine (4 rows/load in flight)
    int quad = lane >> 4;                  // which of 4 rows per load
    int l16  = lane & 15;                  // 8-dim group within row
    for (int i = 0; i < 8; ++i) {
        int rl = w * 8 + i;
        int node = b * RB + sub * SRB + rl;
        int s0 = (int)ex[rl];
        int e0 = s0 + (int)cnt[rl];
        if (e0 > SCAP) e0 = SCAP;          // statistically unreachable guard
        float a0=0.f,a1=0.f,a2=0.f,a3=0.f,a4=0.f,a5=0.f,a6=0.f,a7=0.f;
        for (int base = s0; base < e0; base += 64) {
            int rem = e0 - base; if (rem > 64) rem = 64;
            int px = 0, py = 0;
            if (lane < rem) {
                unsigned pk = list[base + lane];            // LDS, conflict-free
                px = (int)(pk & 0xFFFFu);
                py = __float_as_int(exp_scores[pk >> 16]);  // 4KB: L1-resident
            }
            for (int jj = 0; jj < rem; jj += 16) {
                #pragma unroll
                for (int k = 0; k < 16; k += 4) {
                    if (jj + k < rem) {    // wave-uniform guard
                        int idx = jj + k + quad;
                        int   c = __shfl(px, idx);          // 0 beyond rem -> wv*0
                        float wv = __int_as_float(__shfl(py, idx));
                        const __half2* hp = hinl + (long)c * (D / 2) + l16 * 4;
                        uint4 hv = *(const uint4*)hp;       // 8 halves (16B)
                        float2 f0 = __half22float2(*(const __half2*)&hv.x);
                        float2 f1 = __half22float2(*(const __half2*)&hv.y);
                        float2 f2 = __half22float2(*(const __half2*)&hv.z);
                        float2 f3 = __half22float2(*(const __half2*)&hv.w);
                        a0 += wv * f0.x; a1 += wv * f0.y;
                        a2 += wv * f1.x; a3 += wv * f1.y;
                        a4 += wv * f2.x; a5 += wv * f2.y;
                        a6 += wv * f3.x; a7 += wv * f3.y;
                    }
                }
            }
        }
        #define COMB(x) x += __shfl(x, lane ^ 16); x += __shfl(x, lane ^ 32);
        COMB(a0) COMB(a1) COMB(a2) COMB(a3) COMB(a4) COMB(a5) COMB(a6) COMB(a7)
        #undef COMB
        if (lane < 32 && node < N_NODES) { // 32 lanes cover the 512B row store
            float4 o;
            int hi = (lane >> 4) & 1;      // 0: dims 0-3 of group, 1: dims 4-7
            if (hi) { o.x = a4*inv; o.y = a5*inv; o.z = a6*inv; o.w = a7*inv; }
            else    { o.x = a0*inv; o.y = a1*inv; o.z = a2*inv; o.w = a3*inv; }
            *(float4*)(out + (long)node * D + l16 * 8 + hi * 4) = o;
        }
    }
}

extern "C" void kernel_launch(void* const* d_in, const int* in_sizes, int n_in,
                              void* d_out, int out_size, void* d_ws, size_t ws_size,
                              hipStream_t stream) {
    const float* inlayer  = (const float*)d_in[0];
    const float* dual     = (const float*)d_in[1];
    const float* conv_w   = (const float*)d_in[2];
    const float* conv_b   = (const float*)d_in[3];
    const int*   edge_idx = (const int*)d_in[4];   // [2, NNZ]: rows then cols
    const int*   edge_rel = (const int*)d_in[5];
    float* out = (float*)d_out;
    const int* rows = edge_idx;
    const int* cols = edge_idx + NNZ;

    // workspace layout (16B aligned) — total ~25.7 MB
    char* ws = (char*)d_ws;
    float*              exp_scores = (float*)             (ws);             // 4 KB
    float*              denom      = (float*)             (ws + 4096);      // 4 B (memset)
    unsigned*           bincur     = (unsigned*)          (ws + 8192);      // 98*64B (memset)
    unsigned*           scur       = (unsigned*)          (ws + 16384);     // 784*64B (memset)
    unsigned long long* binbuf     = (unsigned long long*)(ws + 69632);     // 8.03 MB
    unsigned*           subbuf     = (unsigned*)          (ws + 69632 + 8028160);           // 4.8 MB
    __half2*            hinl       = (__half2*)           (ws + 69632 + 8028160 + 4816896); // 12.8 MB

    // zero denom + bincur + scur: ws+4096 .. ws+16384+784*64 (61.0 KB)
    hipMemsetAsync(ws + 4096, 0, 16384 + 784 * 64 - 4096, stream);

    k0_kernel<<<K0B, 256, 0, stream>>>(dual, conv_w, conv_b, inlayer,
                                       exp_scores, hinl);
    k1_kernel<<<NCH, K1T, 0, stream>>>(rows, cols, edge_rel, exp_scores,
                                       denom, bincur, binbuf);
    k2a_kernel<<<NBIN * 4, 512, 0, stream>>>(bincur, binbuf, scur, subbuf);
    k3_kernel<<<NSUB, 512, 0, stream>>>(scur, subbuf, exp_scores, denom,
                                        hinl, out);
}

// Round 19
// 137.369 us; speedup vs baseline: 1.0151x; 1.0151x over previous
//
#include <hip/hip_runtime.h>
#include <hip/hip_fp16.h>
#include <math.h>

#define N_NODES 50000
#define N_REL   1000
#define D       128
#define NNZ     800000

#define RB    512                  // rows per k1 bin (full-line write runs)
#define NBIN  98                   // ceil(50000/512)
#define CAP   10240                // slots/bin: mean 8184, sigma ~90
#define CH    2048                 // edges per partition chunk (391 blocks: k1 optimum)
#define NCH   ((NNZ + CH - 1) / CH)   // 391 chunks/blocks
#define K1T   512
#define K1E   (CH / K1T)           // 4 edges/thread
#define QW    2560                 // k2a quarter-window packs (CAP/4)
#define QE    (QW / 512)           // 5 staged packs/thread in k2a
#define SRB   64                   // rows per sub-bin slice
#define SCAP  1536                 // slots per sub-bin (mean 1023, +16 sigma)
#define NSUB  (NBIN * 8)           // 784 sub-bins

// ===== K0: relation scores — one wave per relation ==============================
__global__ void __launch_bounds__(512)
k0_kernel(const float* __restrict__ dual, const float* __restrict__ conv_w,
          const float* __restrict__ conv_b, float* __restrict__ exp_scores) {
    int wid = (blockIdx.x * 512 + threadIdx.x) >> 6;
    int lane = threadIdx.x & 63;
    if (wid >= N_REL) return;
    const float* row = dual + (long)wid * D;
    float s = row[lane] * conv_w[lane] + row[lane + 64] * conv_w[lane + 64];
    #pragma unroll
    for (int off = 32; off > 0; off >>= 1) s += __shfl_down(s, off);
    if (lane == 0) {
        float v = s + conv_b[0];
        v = (v >= 0.f) ? v : 0.01f * v;            // leaky_relu
        exp_scores[wid] = expf(v);                 // scores ~N(0,1): safe
    }
}

// ===== K1: f32->f16 convert + LDS-sorted bin partition + block denom partial =====
// Edge pack (u64): col:16 | rel:10 | rowlocal:9. 98 bins -> ~21-edge (168B) runs.
// Convert stays HERE: it hides in k1's latency bubbles (r18 proved hoisting costs).
__global__ void __launch_bounds__(K1T)
k1_kernel(const int* __restrict__ rows, const int* __restrict__ cols,
          const int* __restrict__ rel, const float* __restrict__ inlayer,
          const float* __restrict__ exp_scores, float* __restrict__ denom,
          unsigned* __restrict__ bincur, unsigned long long* __restrict__ binbuf,
          __half2* __restrict__ hinl) {
    __shared__ unsigned long long sbuf[CH];     // 16 KB chunk staging (bin-sorted)
    __shared__ unsigned char sbin[CH];          // 2 KB per-slot bin id (98 < 256)
    __shared__ unsigned lcnt[NBIN], lstart[NBIN], lgb[NBIN];
    __shared__ float fpart[8];
    __shared__ unsigned w0sum;
    int t = threadIdx.x;
    int gtid = blockIdx.x * K1T + t;
    int lane = t & 63, w = t >> 6;

    // --- f32 -> f16 convert (grid-stride float4, coalesced) ---
    const float4* src4 = (const float4*)inlayer;
    uint2* dst2 = (uint2*)hinl;
    for (int i = gtid; i < N_NODES * D / 4; i += NCH * K1T) {
        float4 f = src4[i];
        __half2 h0 = __floats2half2_rn(f.x, f.y);
        __half2 h1 = __floats2half2_rn(f.z, f.w);
        uint2 o; o.x = *(unsigned*)&h0; o.y = *(unsigned*)&h1;
        dst2[i] = o;
    }

    // --- partition this block's 2048-edge chunk ---
    if (t < NBIN) lcnt[t] = 0;
    __syncthreads();

    int n = NNZ - blockIdx.x * CH; if (n > CH) n = CH;   // tail = 1280 (mult of 4)
    int base4 = blockIdx.x * (CH / 4);

    int       ebin[K1E];
    unsigned  erank[K1E];
    unsigned long long epack[K1E];
    float dsum = 0.f;
    bool has = (4 * t < n);
    int4 rr, cc, qq;
    if (has) {
        rr = ((const int4*)rows)[base4 + t];
        cc = ((const int4*)cols)[base4 + t];
        qq = ((const int4*)rel)[base4 + t];
    }
    #pragma unroll
    for (int k = 0; k < K1E; ++k) {
        if (has) {
            int r = (k == 0) ? rr.x : (k == 1) ? rr.y : (k == 2) ? rr.z : rr.w;
            int c = (k == 0) ? cc.x : (k == 1) ? cc.y : (k == 2) ? cc.z : cc.w;
            int q = (k == 0) ? qq.x : (k == 1) ? qq.y : (k == 2) ? qq.z : qq.w;
            int b = r >> 9;
            epack[k] = (unsigned long long)(unsigned)c
                     | ((unsigned long long)(unsigned)q << 16)
                     | ((unsigned long long)(unsigned)(r & 511) << 26);
            ebin[k] = b;
            erank[k] = atomicAdd(&lcnt[b], 1u);
            dsum += exp_scores[q];                 // 4KB table: L1-resident
        } else ebin[k] = -1;
    }
    // wave-level denom partial
    #pragma unroll
    for (int off = 32; off > 0; off >>= 1) dsum += __shfl_down(dsum, off);
    if (lane == 0) fpart[w] = dsum;
    __syncthreads();

    // exclusive scan of 98 bin counts (2 waves) + reserve global runs
    unsigned v = (t < NBIN) ? lcnt[t] : 0u;
    if (t < 128) {
        #pragma unroll
        for (int off = 1; off < 64; off <<= 1) {
            unsigned y = __shfl_up(v, off);
            if (lane >= off) v += y;
        }
        if (t == 63) w0sum = v;
    }
    if (t == 0) {                          // one denom atomic per block
        float s = 0.f;
        #pragma unroll
        for (int k = 0; k < 8; ++k) s += fpart[k];
        atomicAdd(denom, s);
    }
    __syncthreads();
    if (t >= 64 && t < 128) v += w0sum;
    if (t < NBIN) {
        lstart[t] = v - lcnt[t];
        lgb[t] = atomicAdd(&bincur[t * 16], lcnt[t]);   // padded cursors: 1/line
    }
    __syncthreads();

    // LDS scatter into bin-sorted order
    #pragma unroll
    for (int k = 0; k < K1E; ++k) {
        if (ebin[k] >= 0) {
            unsigned p = lstart[ebin[k]] + erank[k];
            sbuf[p] = epack[k];
            sbin[p] = (unsigned char)ebin[k];
        }
    }
    __syncthreads();

    // coalesced run writes: ~21-edge (168B) runs -> mostly full 64B lines
    #pragma unroll
    for (int k = 0; k < K1E; ++k) {
        int j = k * K1T + t;
        if (j < n) {
            int b = sbin[j];
            unsigned slot = lgb[b] + (unsigned)j - lstart[b];
            if (slot < CAP)
                binbuf[(unsigned long long)b * CAP + slot] = sbuf[j];
        }
    }
}

// ===== K2a: repartition bin -> 8 slice sub-bins (each edge read/written once) ====
// Block = (bin, quarter-window). Runs avg 320 edges (1.3KB): fully line-aligned.
// Out pack (u32): col:16 | rel:10 | row6(within slice) @26.
__global__ void __launch_bounds__(512)
k2a_kernel(const unsigned* __restrict__ bincur,
           const unsigned long long* __restrict__ binbuf,
           unsigned* __restrict__ scur, unsigned* __restrict__ subbuf) {
    __shared__ unsigned sbuf[QW];          // 10 KB slice-sorted packs
    __shared__ unsigned char ssl[QW];      // 2.5 KB slice ids
    __shared__ unsigned lcnt[8], lstart[8], lgb[8];
    int t = threadIdx.x;
    int b = blockIdx.x >> 2;               // bin 0..97
    int q = blockIdx.x & 3;                // quarter window
    unsigned nb = bincur[b * 16]; if (nb > CAP) nb = CAP;
    int lo = q * QW;
    int n = (int)nb - lo; if (n > QW) n = QW; if (n < 0) n = 0;

    if (t < 8) lcnt[t] = 0;
    __syncthreads();

    unsigned pk32[QE]; int esl[QE]; unsigned erank[QE];
    #pragma unroll
    for (int k = 0; k < QE; ++k) {
        int j = k * 512 + t;
        if (j < n) {
            unsigned long long pk = binbuf[(unsigned long long)b * CAP + lo + j];
            unsigned u = (unsigned)(pk >> 26) & 511u;
            int s = (int)(u >> 6);
            pk32[k] = ((unsigned)pk & 0x3FFFFFFu) | ((u & 63u) << 26);
            esl[k] = s;
            erank[k] = atomicAdd(&lcnt[s], 1u);
        } else esl[k] = -1;
    }
    __syncthreads();

    if (t < 8) lgb[t] = atomicAdd(&scur[(b * 8 + t) * 16], lcnt[t]);
    if (t == 0) {
        unsigned acc = 0;
        #pragma unroll
        for (int s = 0; s < 8; ++s) { lstart[s] = acc; acc += lcnt[s]; }
    }
    __syncthreads();

    #pragma unroll
    for (int k = 0; k < QE; ++k) {
        if (esl[k] >= 0) {
            unsigned p = lstart[esl[k]] + erank[k];
            sbuf[p] = pk32[k];
            ssl[p] = (unsigned char)esl[k];
        }
    }
    __syncthreads();

    // coalesced run writes: avg 320-edge (1.3KB) runs
    #pragma unroll
    for (int k = 0; k < QE; ++k) {
        int j = k * 512 + t;
        if (j < n) {
            int s = ssl[j];
            unsigned slot = lgb[s] + (unsigned)j - lstart[s];
            if (slot < SCAP)
                subbuf[(unsigned)(b * 8 + s) * SCAP + slot] = sbuf[j];
        }
    }
}

// ===== K3: gather — block = sub-bin; reads own 4KB contiguous list ONCE ========
__global__ void __launch_bounds__(512)
k3_kernel(const unsigned* __restrict__ scur, const unsigned* __restrict__ subbuf,
          const float* __restrict__ exp_scores, const float* __restrict__ denom,
          const __half2* __restrict__ hinl, float* __restrict__ out) {
    __shared__ unsigned list[SCAP];        // 6 KB row-sorted (col|rel<<16)
    __shared__ unsigned cnt[SRB], ex[SRB], cur[SRB];
    int t = threadIdx.x, lane = t & 63, w = t >> 6;
    int sid = blockIdx.x;                  // sub-bin 0..783
    int b = sid >> 3, sub = sid & 7;
    unsigned n = scur[sid * 16]; if (n > SCAP) n = SCAP;
    const unsigned* sb = subbuf + (unsigned)sid * SCAP;

    if (t < SRB) cnt[t] = 0;
    float inv = 1.0f / *denom;             // complete after k1; uniform scalar
    __syncthreads();

    // single read of own sub-bin: register-stage + row histogram
    unsigned pkr[3];                       // SCAP/512 = 3, static indexing
    #pragma unroll
    for (int k = 0; k < 3; ++k) {
        int e = k * 512 + t;
        if (e < (int)n) {
            pkr[k] = sb[e];                // contiguous, coalesced
            atomicAdd(&cnt[pkr[k] >> 26], 1u);
        }
    }
    __syncthreads();

    // wave 0: exclusive scan of 64 row counts
    if (t < 64) {
        unsigned c0 = cnt[t];
        unsigned v = c0;
        #pragma unroll
        for (int off = 1; off < 64; off <<= 1) {
            unsigned y = __shfl_up(v, off);
            if (lane >= off) v += y;
        }
        ex[t] = v - c0;
        cur[t] = v - c0;
    }
    __syncthreads();

    // reg -> LDS row-sorted scatter
    #pragma unroll
    for (int k = 0; k < 3; ++k) {
        int e = k * 512 + t;
        if (e < (int)n) {
            unsigned idx = atomicAdd(&cur[pkr[k] >> 26], 1u);
            if (idx < SCAP) list[idx] = pkr[k] & 0x3FFFFFFu;
        }
    }
    __syncthreads();

    // gather: wave w owns rows w*8 .. w*8+7; quad engine (4 rows/load in flight)
    int quad = lane >> 4;                  // which of 4 rows per load
    int l16  = lane & 15;                  // 8-dim group within row
    for (int i = 0; i < 8; ++i) {
        int rl = w * 8 + i;
        int node = b * RB + sub * SRB + rl;
        int s0 = (int)ex[rl];
        int e0 = s0 + (int)cnt[rl];
        if (e0 > SCAP) e0 = SCAP;          // statistically unreachable guard
        float a0=0.f,a1=0.f,a2=0.f,a3=0.f,a4=0.f,a5=0.f,a6=0.f,a7=0.f;
        for (int base = s0; base < e0; base += 64) {
            int rem = e0 - base; if (rem > 64) rem = 64;
            int px = 0, py = 0;
            if (lane < rem) {
                unsigned pk = list[base + lane];            // LDS, conflict-free
                px = (int)(pk & 0xFFFFu);
                py = __float_as_int(exp_scores[pk >> 16]);  // 4KB: L1-resident
            }
            for (int jj = 0; jj < rem; jj += 16) {
                #pragma unroll
                for (int k = 0; k < 16; k += 4) {
                    if (jj + k < rem) {    // wave-uniform guard
                        int idx = jj + k + quad;
                        int   c = __shfl(px, idx);          // 0 beyond rem -> wv*0
                        float wv = __int_as_float(__shfl(py, idx));
                        const __half2* hp = hinl + (long)c * (D / 2) + l16 * 4;
                        uint4 hv = *(const uint4*)hp;       // 8 halves (16B)
                        float2 f0 = __half22float2(*(const __half2*)&hv.x);
                        float2 f1 = __half22float2(*(const __half2*)&hv.y);
                        float2 f2 = __half22float2(*(const __half2*)&hv.z);
                        float2 f3 = __half22float2(*(const __half2*)&hv.w);
                        a0 += wv * f0.x; a1 += wv * f0.y;
                        a2 += wv * f1.x; a3 += wv * f1.y;
                        a4 += wv * f2.x; a5 += wv * f2.y;
                        a6 += wv * f3.x; a7 += wv * f3.y;
                    }
                }
            }
        }
        #define COMB(x) x += __shfl(x, lane ^ 16); x += __shfl(x, lane ^ 32);
        COMB(a0) COMB(a1) COMB(a2) COMB(a3) COMB(a4) COMB(a5) COMB(a6) COMB(a7)
        #undef COMB
        if (lane < 32 && node < N_NODES) { // 32 lanes cover the 512B row store
            float4 o;
            int hi = (lane >> 4) & 1;      // 0: dims 0-3 of group, 1: dims 4-7
            if (hi) { o.x = a4*inv; o.y = a5*inv; o.z = a6*inv; o.w = a7*inv; }
            else    { o.x = a0*inv; o.y = a1*inv; o.z = a2*inv; o.w = a3*inv; }
            *(float4*)(out + (long)node * D + l16 * 8 + hi * 4) = o;
        }
    }
}

extern "C" void kernel_launch(void* const* d_in, const int* in_sizes, int n_in,
                              void* d_out, int out_size, void* d_ws, size_t ws_size,
                              hipStream_t stream) {
    const float* inlayer  = (const float*)d_in[0];
    const float* dual     = (const float*)d_in[1];
    const float* conv_w   = (const float*)d_in[2];
    const float* conv_b   = (const float*)d_in[3];
    const int*   edge_idx = (const int*)d_in[4];   // [2, NNZ]: rows then cols
    const int*   edge_rel = (const int*)d_in[5];
    float* out = (float*)d_out;
    const int* rows = edge_idx;
    const int* cols = edge_idx + NNZ;

    // workspace layout (16B aligned) — total ~25.7 MB
    char* ws = (char*)d_ws;
    float*              exp_scores = (float*)             (ws);             // 4 KB
    float*              denom      = (float*)             (ws + 4096);      // 4 B (memset)
    unsigned*           bincur     = (unsigned*)          (ws + 8192);      // 98*64B (memset)
    unsigned*           scur       = (unsigned*)          (ws + 16384);     // 784*64B (memset)
    unsigned long long* binbuf     = (unsigned long long*)(ws + 69632);     // 8.03 MB
    unsigned*           subbuf     = (unsigned*)          (ws + 69632 + 8028160);           // 4.8 MB
    __half2*            hinl       = (__half2*)           (ws + 69632 + 8028160 + 4816896); // 12.8 MB

    // zero denom + bincur + scur: ws+4096 .. ws+16384+784*64 (61.0 KB)
    hipMemsetAsync(ws + 4096, 0, 16384 + 784 * 64 - 4096, stream);

    k0_kernel<<<125, 512, 0, stream>>>(dual, conv_w, conv_b, exp_scores);
    k1_kernel<<<NCH, K1T, 0, stream>>>(rows, cols, edge_rel, inlayer, exp_scores,
                                       denom, bincur, binbuf, hinl);
    k2a_kernel<<<NBIN * 4, 512, 0, stream>>>(bincur, binbuf, scur, subbuf);
    k3_kernel<<<NSUB, 512, 0, stream>>>(scur, subbuf, exp_scores, denom,
                                        hinl, out);
}